// Round 13
// baseline (221.642 us; speedup 1.0000x reference)
//
#include <hip/hip_runtime.h>
#include <hip/hip_bf16.h>
#include <math.h>

#define DM    1024
#define SEQL  2048
#define NB    2
#define MTOT  4096   // NB*SEQL

typedef __attribute__((ext_vector_type(8))) short short8;
typedef __attribute__((ext_vector_type(4))) short short4v;
typedef __attribute__((ext_vector_type(4))) float float4v;

// async global->LDS, 16B per lane; LDS dest is wave-uniform base (+ lane*16 implicit)
#define GLDS16(g, l) __builtin_amdgcn_global_load_lds( \
    (const __attribute__((address_space(1))) void*)(g), \
    (__attribute__((address_space(3))) void*)(l), 16, 0, 0)

__device__ __forceinline__ short f2bf(float f) {
  union { float f; unsigned u; } c; c.f = f;
  unsigned r = c.u + 0x7FFFu + ((c.u >> 16) & 1u);  // RNE
  return (short)(r >> 16);
}

// pack two fp32 -> dword of two bf16 (lo=a, hi=b); round-half-up (cheap, P>=0)
__device__ __forceinline__ int packbf(float a, float b) {
  union { float f; unsigned u; } ca, cb; ca.f = a; cb.f = b;
  return (int)__builtin_amdgcn_perm(cb.u + 0x8000u, ca.u + 0x8000u, 0x07060302u);
}

// One launch converting x + 4 weights fp32->bf16.
__global__ __launch_bounds__(256) void cvt_all(
    const float* __restrict__ x, const float* __restrict__ wq, const float* __restrict__ wk,
    const float* __restrict__ wv, const float* __restrict__ wo,
    short* __restrict__ xb, short* __restrict__ wqb, short* __restrict__ wkb,
    short* __restrict__ wvb, short* __restrict__ wob) {
  const int n4x = MTOT * DM / 4;        // 1,048,576
  int i = blockIdx.x * 256 + threadIdx.x;
  const float* s; short* d; int off;
  if (i < n4x) { s = x; d = xb; off = i; }
  else {
    int j = i - n4x;
    int sel = j >> 18;                  // DM*DM/4 = 262144 = 2^18
    off = j & 0x3FFFF;
    s = (sel == 0) ? wq : (sel == 1) ? wk : (sel == 2) ? wv : wo;
    d = (sel == 0) ? wqb : (sel == 1) ? wkb : (sel == 2) ? wvb : wob;
  }
  float4 v = ((const float4*)s)[off];
  short4v o;
  o.x = f2bf(v.x); o.y = f2bf(v.y); o.z = f2bf(v.z); o.w = f2bf(v.w);
  ((short4v*)d)[off] = o;
}

// Fused QKV projection (v14 exact, measured best: 45.0us, FETCH 30MB).
__global__ __launch_bounds__(256, 3) void qkv_kernel(
    const short* __restrict__ A,
    const short* __restrict__ B0, const short* __restrict__ B1, const short* __restrict__ B2,
    short* __restrict__ out0, short* __restrict__ out1, short* __restrict__ out2,
    const float* __restrict__ cosp, const float* __restrict__ sinp)
{
  __shared__ short As[2][128 * 32];
  __shared__ short Bs[2][128 * 32];
  const int t = threadIdx.x;
  const int w = t >> 6, lane = t & 63;
  const int quad = lane >> 4, l16 = lane & 15;
  const int wm = w >> 1, wn = w & 1;

  // XCD remap: h = hw linear id; xcd = h&7 owns y in [xcd*4, xcd*4+4).
  const int h = (blockIdx.z << 8) + (blockIdx.y << 3) + blockIdx.x;
  const int xcd = h & 7, slot = h >> 3;          // slot 0..95
  const int ly = xcd * 4 + (slot & 3);           // 0..31
  const int lx = (slot >> 2) & 7;                // 0..7
  const int lz = slot >> 5;                      // 0..2
  const int bm = ly * 128, bn = lx * 128;

  const short* Bw = (lz == 0) ? B0 : ((lz == 1) ? B1 : B2);

  float4v acc[4][4];
#pragma unroll
  for (int i = 0; i < 4; ++i)
#pragma unroll
    for (int j = 0; j < 4; ++j) { float4v z = {0.f, 0.f, 0.f, 0.f}; acc[i][j] = z; }

  auto stage = [&](int k0, int p) {
#pragma unroll
    for (int i = 0; i < 2; ++i) {
      const int row = (i * 256 + t) >> 2, kc = (i * 256 + t) & 3;
      GLDS16(A  + (size_t)(bm + row) * DM + k0 + kc * 8, &As[p][(i * 256 + w * 64) * 8]);
      GLDS16(Bw + (size_t)(bn + row) * DM + k0 + kc * 8, &Bs[p][(i * 256 + w * 64) * 8]);
    }
  };

  stage(0, 0);
  for (int ki = 0; ki < 32; ++ki) {
    const int p = ki & 1;
    __syncthreads();
    if (ki < 31) stage((ki + 1) * 32, p ^ 1);
    short8 af[4], bf[4];
#pragma unroll
    for (int mt = 0; mt < 4; ++mt) af[mt] = *(const short8*)&As[p][(wm * 64 + mt * 16 + l16) * 32 + quad * 8];
#pragma unroll
    for (int nt = 0; nt < 4; ++nt) bf[nt] = *(const short8*)&Bs[p][(wn * 64 + nt * 16 + l16) * 32 + quad * 8];
#pragma unroll
    for (int mt = 0; mt < 4; ++mt)
#pragma unroll
      for (int nt = 0; nt < 4; ++nt)
        acc[mt][nt] = __builtin_amdgcn_mfma_f32_16x16x32_bf16(af[mt], bf[nt], acc[mt][nt], 0, 0, 0);
  }

  if (lz < 2) {
    short* qo = (lz == 0) ? out0 : out1;
    const float sc = (lz == 0) ? 0.18033688011112042f : 1.0f;  // 0.125*log2(e) for Q
#pragma unroll
    for (int mt = 0; mt < 4; ++mt)
#pragma unroll
      for (int r = 0; r < 4; ++r) {
        int grow = bm + wm * 64 + mt * 16 + quad * 4 + r;
        int s = grow & (SEQL - 1);
        int base = grow * DM + bn + wn * 64;
#pragma unroll
        for (int nt = 0; nt < 2; ++nt) {
          int d1 = nt * 16 + l16;  // 0..31
          float q1 = acc[mt][nt][r], q2 = acc[mt][nt + 2][r];
          float c1 = cosp[s * 64 + d1] * sc,      s1 = sinp[s * 64 + d1] * sc;
          float c2 = cosp[s * 64 + 32 + d1] * sc, s2 = sinp[s * 64 + 32 + d1] * sc;
          qo[base + d1]      = f2bf(q1 * c1 - q2 * s1);
          qo[base + 32 + d1] = f2bf(q2 * c2 + q1 * s2);
        }
      }
  } else {
    short* vo = out2;
#pragma unroll
    for (int mt = 0; mt < 4; ++mt)
#pragma unroll
      for (int nt = 0; nt < 4; ++nt) {
        int gc = bn + wn * 64 + nt * 16 + l16;
        int g0 = bm + wm * 64 + mt * 16 + quad * 4;
        short4v pk;
#pragma unroll
        for (int r = 0; r < 4; ++r) pk[r] = f2bf(acc[mt][nt][r]);
        *(short4v*)&vo[(size_t)gc * MTOT + g0] = pk;
      }
  }
}

// Flash attention v17: ONE q-tile per block (pairing dropped; v16's shuffle
// transpose reverted — __shfl is ds_bpermute, an LDS-pipe op, and it slowed
// the S^T->PV path). Inner pipeline = v9's proven 3-barrier counted-vmcnt,
// tile-B path verbatim. Single-tile P strips: LDS 68->50KB AND grid 512->
// 1024 blocks => 3 blocks/CU = 24 waves/CU (+50% TLP; v16 showed occupancy
// was grid-capped at 2/CU). Longest tiles (high qt) dispatched first.
// Per-tile math bit-identical to v9 -> absmax unchanged.
__global__ __launch_bounds__(512, 6) void attn_kernel(
    const short* __restrict__ Q, const short* __restrict__ K,
    const short* __restrict__ Vt, short* __restrict__ O)
{
  __shared__ short smem[25600];        // 50 KB: Ks 16K | Vs 16K | P strips 18K
  short* Ks = smem;                    // [128 n][8 chunks], xor-swizzled
  short* Vs = smem + 8192;             // [64 d][16 chunks], xor-swizzled
  const int t = threadIdx.x;
  const int wid = t >> 6, lane = t & 63;
  const int quad = lane >> 4, l16 = lane & 15;
  const int g = wid >> 2;              // k-half group: 0 -> k 0..63, 1 -> 64..127
  const int qg = wid & 3;              // q-row group (16 rows)
  short* Pl = smem + 16384 + wid * 1152;   // per-wave strip [16 q][72]
  const int qt = 31 - blockIdx.x;      // longest first for tail packing
  const int bh = blockIdx.y, b = bh >> 4, h = bh & 15;
  const int rowbase = b * SEQL, colbase = h * 64;
  const int nkt = (qt >> 1) + 1;
  const int q = qt * 64 + qg * 16 + l16;

  // Q fragment (lane=q, elems=d): MFMA B-operand for S^T = K·Q^T (pre-scaled)
  short8 aq[2];
#pragma unroll
  for (int kk = 0; kk < 2; ++kk)
    aq[kk] = *(const short8*)&Q[(size_t)(rowbase + q) * DM + colbase + kk * 32 + quad * 8];

  float4v o_[4];                       // O: row q=quad*4+r, col d=dt*16+l16 (k-half partial)
#pragma unroll
  for (int j = 0; j < 4; ++j) { float4v z = {0.f, 0.f, 0.f, 0.f}; o_[j] = z; }
  float lsum = 0.f;                    // per-lane partial row-sum, indexed by q = l16

  const short* Kbase0 = K + (size_t)rowbase * DM + colbase;
  const short* Vbase0 = Vt + (size_t)colbase * MTOT + rowbase;

  auto stageK = [&](int kt) {          // K-tile (128 rows x 64 d), 2 GLDS/thread
#pragma unroll
    for (int j = 0; j < 2; ++j) {
      int i = j * 512 + t;
      int n = i >> 3, c = (i & 7) ^ (n & 7);
      GLDS16(Kbase0 + (size_t)(kt * 128 + n) * DM + c * 8, Ks + (j * 512 + wid * 64) * 8);
    }
  };
  auto stageV = [&](int kt) {          // V-tile (64 d x 128 k), 2 GLDS/thread
#pragma unroll
    for (int j = 0; j < 2; ++j) {
      int i = j * 512 + t;
      int d = i >> 4, c = (i & 15) ^ (d & 7);
      GLDS16(Vbase0 + (size_t)d * MTOT + kt * 128 + c * 8, Vs + (j * 512 + wid * 64) * 8);
    }
  };

  stageK(0);
  stageV(0);
  for (int kt = 0; kt < nkt; ++kt) {
    // K(t) landed in all waves; V(t) (2 newest GLDS/thread) stays in flight.
    asm volatile("s_waitcnt vmcnt(2)" ::: "memory");
    __builtin_amdgcn_s_barrier();
    __builtin_amdgcn_sched_barrier(0);

    const bool diag = (kt == nkt - 1);

    // --- S^T = K Q^T on this wave's 4 nt-subtiles; exp2; P^T -> strip (b64) ---
#pragma unroll
    for (int ntl = 0; ntl < 4; ++ntl) {
      const int nt = g * 4 + ntl;
      const int n = nt * 16 + l16;
      short8 bk0 = *(const short8*)&Ks[(n * 8 + (quad ^ (n & 7))) * 8];
      short8 bk1 = *(const short8*)&Ks[(n * 8 + ((4 + quad) ^ (n & 7))) * 8];
      const int kb = kt * 128 + nt * 16 + quad * 4;
      float4v zz = {0.f, 0.f, 0.f, 0.f};
      __builtin_amdgcn_s_setprio(1);
      float4v s = __builtin_amdgcn_mfma_f32_16x16x32_bf16(bk0, aq[0], zz, 0, 0, 0);
      s = __builtin_amdgcn_mfma_f32_16x16x32_bf16(bk1, aq[1], s, 0, 0, 0);
      __builtin_amdgcn_s_setprio(0);
      float pb[4];
#pragma unroll
      for (int r = 0; r < 4; ++r) {
        float pv = (diag && (kb + r > q)) ? 0.f : __builtin_amdgcn_exp2f(s[r]);
        lsum += pv; pb[r] = pv;
      }
      *(int2*)&Pl[l16 * 72 + ntl * 16 + quad * 4] =
          make_int2(packbf(pb[0], pb[1]), packbf(pb[2], pb[3]));
    }

    // V(t) landed (only V(t)'s 2 loads outstanding) + everyone done with Ks.
    asm volatile("s_waitcnt vmcnt(0)" ::: "memory");
    __builtin_amdgcn_s_barrier();
    __builtin_amdgcn_sched_barrier(0);

    // K(t+1) prefetch into Ks, hidden under PV(t).
    if (kt + 1 < nkt) stageK(kt + 1);

    // --- O += P V over this wave's 64-k half ---
#pragma unroll
    for (int kk = 0; kk < 2; ++kk) {
      short8 ap = *(const short8*)&Pl[l16 * 72 + kk * 32 + quad * 8];
      const int c0 = g * 8 + kk * 4 + quad;     // k-chunk index in Vs
      __builtin_amdgcn_s_setprio(1);
#pragma unroll
      for (int dt = 0; dt < 4; ++dt) {
        const int d = dt * 16 + l16;
        short8 bv = *(const short8*)&Vs[(d * 16 + (c0 ^ (d & 7))) * 8];
        o_[dt] = __builtin_amdgcn_mfma_f32_16x16x32_bf16(ap, bv, o_[dt], 0, 0, 0);
      }
      __builtin_amdgcn_s_setprio(0);
    }

    // Everyone done reading Vs (reads consumed by MFMAs above); release Vs.
    __builtin_amdgcn_s_barrier();
    __builtin_amdgcn_sched_barrier(0);

    // V(t+1) prefetch into Vs, hidden under next iter's S^T phase.
    if (kt + 1 < nkt) stageV(kt + 1);
  }

  // --- quad-reduce lsum within wave (sum over this wave's k-half); per q=l16 ---
  lsum += __shfl_xor(lsum, 16); lsum += __shfl_xor(lsum, 32);

  // --- merge the two k-half groups via LDS, then normalize + store (group 0) ---
  __syncthreads();
  float* Ored = (float*)smem;                   // [4 qg][16 q][66]
  float* Lred = (float*)smem + 4224;            // [4 qg][16 q]
  if (g == 1) {
    const int base = (qg * 16) * 66;
#pragma unroll
    for (int dt = 0; dt < 4; ++dt)
#pragma unroll
      for (int r = 0; r < 4; ++r)
        Ored[base + (quad * 4 + r) * 66 + dt * 16 + l16] = o_[dt][r];
    if (lane < 16) Lred[qg * 16 + l16] = lsum;
  }
  __syncthreads();
  if (g == 0) {
    // totals are indexed by q = l16; O rows are q = quad*4+r -> transpose the
    // normalizer via lane shuffles (source lane s = quad*4+r has l16 == s).
    const float tot = lsum + Lred[qg * 16 + l16];
    float ir[4];
#pragma unroll
    for (int r = 0; r < 4; ++r) ir[r] = 1.f / __shfl(tot, quad * 4 + r);
    const int base = (qg * 16) * 66;
#pragma unroll
    for (int dt = 0; dt < 4; ++dt)
#pragma unroll
      for (int r = 0; r < 4; ++r) {
        float v = o_[dt][r] + Ored[base + (quad * 4 + r) * 66 + dt * 16 + l16];
        int grow = rowbase + qt * 64 + qg * 16 + quad * 4 + r;
        int gcol = colbase + dt * 16 + l16;
        O[(size_t)grow * DM + gcol] = f2bf(v * ir[r]);
      }
  }
}

// Output projection (R3-proven original): out = attn x Wo^T, 128m x 64n tiles.
__global__ __launch_bounds__(256, 2) void gemm_out(
    const short* __restrict__ A, const short* __restrict__ B,
    float* __restrict__ out)
{
  __shared__ short As[2][128 * 32];
  __shared__ short Bs[2][64 * 32];
  const int t = threadIdx.x;
  const int w = t >> 6, lane = t & 63;
  const int quad = lane >> 4, l16 = lane & 15;
  const int wm = w >> 1, wn = w & 1;
  const int bm = blockIdx.y * 128, bn = blockIdx.x * 64;

  float4v acc[4][2];
#pragma unroll
  for (int i = 0; i < 4; ++i)
#pragma unroll
    for (int j = 0; j < 2; ++j) { float4v z = {0.f, 0.f, 0.f, 0.f}; acc[i][j] = z; }

  auto stage = [&](int k0, int p) {
#pragma unroll
    for (int i = 0; i < 2; ++i) {
      const int row = (i * 256 + t) >> 2, kc = (i * 256 + t) & 3;
      GLDS16(A + (size_t)(bm + row) * DM + k0 + kc * 8, &As[p][(i * 256 + w * 64) * 8]);
    }
    {
      const int row = t >> 2, kc = t & 3;
      GLDS16(B + (size_t)(bn + row) * DM + k0 + kc * 8, &Bs[p][(w * 64) * 8]);
    }
  };

  stage(0, 0);
  for (int ki = 0; ki < 32; ++ki) {
    const int p = ki & 1;
    __syncthreads();
    if (ki < 31) stage((ki + 1) * 32, p ^ 1);
    short8 af[4], bf[2];
#pragma unroll
    for (int mt = 0; mt < 4; ++mt) af[mt] = *(const short8*)&As[p][(wm * 64 + mt * 16 + l16) * 32 + quad * 8];
#pragma unroll
    for (int nt = 0; nt < 2; ++nt) bf[nt] = *(const short8*)&Bs[p][(wn * 32 + nt * 16 + l16) * 32 + quad * 8];
#pragma unroll
    for (int mt = 0; mt < 4; ++mt)
#pragma unroll
      for (int nt = 0; nt < 2; ++nt)
        acc[mt][nt] = __builtin_amdgcn_mfma_f32_16x16x32_bf16(af[mt], bf[nt], acc[mt][nt], 0, 0, 0);
  }

#pragma unroll
  for (int mt = 0; mt < 4; ++mt)
#pragma unroll
    for (int nt = 0; nt < 2; ++nt)
#pragma unroll
      for (int r = 0; r < 4; ++r) {
        int grow = bm + wm * 64 + mt * 16 + quad * 4 + r;
        int gcol = bn + wn * 32 + nt * 16 + l16;
        out[(size_t)grow * DM + gcol] = acc[mt][nt][r];
      }
}

extern "C" void kernel_launch(void* const* d_in, const int* in_sizes, int n_in,
                              void* d_out, int out_size, void* d_ws, size_t ws_size,
                              hipStream_t stream) {
  const float* x    = (const float*)d_in[0];
  const float* cosp = (const float*)d_in[1];
  const float* sinp = (const float*)d_in[2];
  const float* Wq   = (const float*)d_in[3];
  const float* Wk   = (const float*)d_in[4];
  const float* Wv   = (const float*)d_in[5];
  const float* Wo   = (const float*)d_in[6];

  char* ws = (char*)d_ws;
  const size_t XB = (size_t)MTOT * DM * 2;  // 8 MB
  const size_t WB = (size_t)DM * DM * 2;    // 2 MB
  short* xb    = (short*)(ws);
  short* wqb   = (short*)(ws + XB);
  short* wkb   = (short*)(ws + XB + 1 * WB);
  short* wvb   = (short*)(ws + XB + 2 * WB);
  short* wob   = (short*)(ws + XB + 3 * WB);
  short* Qb    = (short*)(ws + XB + 4 * WB);
  short* Kb    = (short*)(ws + XB + 4 * WB + XB);
  short* Vtb   = (short*)(ws + XB + 4 * WB + 2 * XB);
  short* attnb = xb;  // x dead after QKV GEMMs; reuse its slot

  const int n4tot = (MTOT * DM + 4 * DM * DM) / 4;  // 2,097,152
  hipLaunchKernelGGL(cvt_all, dim3(n4tot / 256), dim3(256), 0, stream,
                     x, Wq, Wk, Wv, Wo, xb, wqb, wkb, wvb, wob);

  hipLaunchKernelGGL(qkv_kernel, dim3(DM / 128, MTOT / 128, 3), dim3(256), 0, stream,
                     xb, wqb, wkb, wvb, Qb, Kb, Vtb, cosp, sinp);

  hipLaunchKernelGGL(attn_kernel, dim3(32, NB * 16), dim3(512), 0, stream,
                     Qb, Kb, Vtb, attnb);

  hipLaunchKernelGGL(gemm_out, dim3(DM / 64, MTOT / 128), dim3(256), 0, stream,
                     attnb, wob, (float*)d_out);
}

// Round 14
// 172.398 us; speedup vs baseline: 1.2856x; 1.2856x over previous
//
#include <hip/hip_runtime.h>
#include <hip/hip_bf16.h>
#include <math.h>

#define DM    1024
#define SEQL  2048
#define NB    2
#define MTOT  4096   // NB*SEQL

typedef __attribute__((ext_vector_type(8))) short short8;
typedef __attribute__((ext_vector_type(4))) short short4v;
typedef __attribute__((ext_vector_type(4))) float float4v;

// async global->LDS, 16B per lane; LDS dest is wave-uniform base (+ lane*16 implicit)
#define GLDS16(g, l) __builtin_amdgcn_global_load_lds( \
    (const __attribute__((address_space(1))) void*)(g), \
    (__attribute__((address_space(3))) void*)(l), 16, 0, 0)

__device__ __forceinline__ short f2bf(float f) {
  union { float f; unsigned u; } c; c.f = f;
  unsigned r = c.u + 0x7FFFu + ((c.u >> 16) & 1u);  // RNE
  return (short)(r >> 16);
}

// pack two fp32 -> dword of two bf16 (lo=a, hi=b); round-half-up (cheap, P>=0)
__device__ __forceinline__ int packbf(float a, float b) {
  union { float f; unsigned u; } ca, cb; ca.f = a; cb.f = b;
  return (int)__builtin_amdgcn_perm(cb.u + 0x8000u, ca.u + 0x8000u, 0x07060302u);
}

// One launch converting x + 4 weights fp32->bf16.
__global__ __launch_bounds__(256) void cvt_all(
    const float* __restrict__ x, const float* __restrict__ wq, const float* __restrict__ wk,
    const float* __restrict__ wv, const float* __restrict__ wo,
    short* __restrict__ xb, short* __restrict__ wqb, short* __restrict__ wkb,
    short* __restrict__ wvb, short* __restrict__ wob) {
  const int n4x = MTOT * DM / 4;        // 1,048,576
  int i = blockIdx.x * 256 + threadIdx.x;
  const float* s; short* d; int off;
  if (i < n4x) { s = x; d = xb; off = i; }
  else {
    int j = i - n4x;
    int sel = j >> 18;                  // DM*DM/4 = 262144 = 2^18
    off = j & 0x3FFFF;
    s = (sel == 0) ? wq : (sel == 1) ? wk : (sel == 2) ? wv : wo;
    d = (sel == 0) ? wqb : (sel == 1) ? wkb : (sel == 2) ? wvb : wob;
  }
  float4 v = ((const float4*)s)[off];
  short4v o;
  o.x = f2bf(v.x); o.y = f2bf(v.y); o.z = f2bf(v.z); o.w = f2bf(v.w);
  ((short4v*)d)[off] = o;
}

// Fused QKV projection (v14 exact, measured best: 45.0us, FETCH 30MB).
__global__ __launch_bounds__(256, 3) void qkv_kernel(
    const short* __restrict__ A,
    const short* __restrict__ B0, const short* __restrict__ B1, const short* __restrict__ B2,
    short* __restrict__ out0, short* __restrict__ out1, short* __restrict__ out2,
    const float* __restrict__ cosp, const float* __restrict__ sinp)
{
  __shared__ short As[2][128 * 32];
  __shared__ short Bs[2][128 * 32];
  const int t = threadIdx.x;
  const int w = t >> 6, lane = t & 63;
  const int quad = lane >> 4, l16 = lane & 15;
  const int wm = w >> 1, wn = w & 1;

  // XCD remap: h = hw linear id; xcd = h&7 owns y in [xcd*4, xcd*4+4).
  const int h = (blockIdx.z << 8) + (blockIdx.y << 3) + blockIdx.x;
  const int xcd = h & 7, slot = h >> 3;          // slot 0..95
  const int ly = xcd * 4 + (slot & 3);           // 0..31
  const int lx = (slot >> 2) & 7;                // 0..7
  const int lz = slot >> 5;                      // 0..2
  const int bm = ly * 128, bn = lx * 128;

  const short* Bw = (lz == 0) ? B0 : ((lz == 1) ? B1 : B2);

  float4v acc[4][4];
#pragma unroll
  for (int i = 0; i < 4; ++i)
#pragma unroll
    for (int j = 0; j < 4; ++j) { float4v z = {0.f, 0.f, 0.f, 0.f}; acc[i][j] = z; }

  auto stage = [&](int k0, int p) {
#pragma unroll
    for (int i = 0; i < 2; ++i) {
      const int row = (i * 256 + t) >> 2, kc = (i * 256 + t) & 3;
      GLDS16(A  + (size_t)(bm + row) * DM + k0 + kc * 8, &As[p][(i * 256 + w * 64) * 8]);
      GLDS16(Bw + (size_t)(bn + row) * DM + k0 + kc * 8, &Bs[p][(i * 256 + w * 64) * 8]);
    }
  };

  stage(0, 0);
  for (int ki = 0; ki < 32; ++ki) {
    const int p = ki & 1;
    __syncthreads();
    if (ki < 31) stage((ki + 1) * 32, p ^ 1);
    short8 af[4], bf[4];
#pragma unroll
    for (int mt = 0; mt < 4; ++mt) af[mt] = *(const short8*)&As[p][(wm * 64 + mt * 16 + l16) * 32 + quad * 8];
#pragma unroll
    for (int nt = 0; nt < 4; ++nt) bf[nt] = *(const short8*)&Bs[p][(wn * 64 + nt * 16 + l16) * 32 + quad * 8];
#pragma unroll
    for (int mt = 0; mt < 4; ++mt)
#pragma unroll
      for (int nt = 0; nt < 4; ++nt)
        acc[mt][nt] = __builtin_amdgcn_mfma_f32_16x16x32_bf16(af[mt], bf[nt], acc[mt][nt], 0, 0, 0);
  }

  if (lz < 2) {
    short* qo = (lz == 0) ? out0 : out1;
    const float sc = (lz == 0) ? 0.18033688011112042f : 1.0f;  // 0.125*log2(e) for Q
#pragma unroll
    for (int mt = 0; mt < 4; ++mt)
#pragma unroll
      for (int r = 0; r < 4; ++r) {
        int grow = bm + wm * 64 + mt * 16 + quad * 4 + r;
        int s = grow & (SEQL - 1);
        int base = grow * DM + bn + wn * 64;
#pragma unroll
        for (int nt = 0; nt < 2; ++nt) {
          int d1 = nt * 16 + l16;  // 0..31
          float q1 = acc[mt][nt][r], q2 = acc[mt][nt + 2][r];
          float c1 = cosp[s * 64 + d1] * sc,      s1 = sinp[s * 64 + d1] * sc;
          float c2 = cosp[s * 64 + 32 + d1] * sc, s2 = sinp[s * 64 + 32 + d1] * sc;
          qo[base + d1]      = f2bf(q1 * c1 - q2 * s1);
          qo[base + 32 + d1] = f2bf(q2 * c2 + q1 * s2);
        }
      }
  } else {
    short* vo = out2;
#pragma unroll
    for (int mt = 0; mt < 4; ++mt)
#pragma unroll
      for (int nt = 0; nt < 4; ++nt) {
        int gc = bn + wn * 64 + nt * 16 + l16;
        int g0 = bm + wm * 64 + mt * 16 + quad * 4;
        short4v pk;
#pragma unroll
        for (int r = 0; r < 4; ++r) pk[r] = f2bf(acc[mt][nt][r]);
        *(short4v*)&vo[(size_t)gc * MTOT + g0] = pk;
      }
  }
}

// Flash attention v9 + XCD remap (v18): paired A/B q-tiles (v17's unpairing
// FAILED: +36% iters, 86us), 3-barrier counted-vmcnt pipeline verbatim.
// NEW: bijective XCD remap (512 = 8x64): each XCD owns 4 bh-groups x 16
// q-pairs, so its K/V working set (4 x 512KB) stays L2-resident (exact
// analog of qkv-v14's remap: FETCH -25%, no dur risk — pure perf permute).
__global__ __launch_bounds__(512, 4) void attn_kernel(
    const short* __restrict__ Q, const short* __restrict__ K,
    const short* __restrict__ Vt, short* __restrict__ O)
{
  __shared__ short smem[34816];        // 68 KB: Ks 16K | Vs 16K | P strips 36K
  short* Ks = smem;                    // [128 n][8 chunks], xor-swizzled
  short* Vs = smem + 8192;             // [64 d][16 chunks], xor-swizzled
  const int t = threadIdx.x;
  const int wid = t >> 6, lane = t & 63;
  const int quad = lane >> 4, l16 = lane & 15;
  const int g = wid >> 2;              // k-half group: 0 -> k 0..63, 1 -> 64..127
  const int qg = wid & 3;              // q-row group (16 rows)
  short* Pl = smem + 16384 + wid * (2 * 16 * 72);  // per-wave strips [2 tiles][16 q][72]

  // XCD remap: hw linear id -> xcd owns bh in [xcd*4, xcd*4+4), all q-pairs.
  const int hw = (blockIdx.y << 4) + blockIdx.x;   // 0..511
  const int xcd = hw & 7, slot = hw >> 3;          // slot 0..63
  const int bh = xcd * 4 + (slot & 3);             // 0..31
  const int qp = slot >> 2;                        // 0..15
  const int qtA = qp, qtB = 31 - qp;
  const int b = bh >> 4, h = bh & 15;
  const int rowbase = b * SEQL, colbase = h * 64;
  const int nktA = (qtA >> 1) + 1, nktB = (qtB >> 1) + 1;
  const int qA = qtA * 64 + qg * 16 + l16;
  const int qB = qtB * 64 + qg * 16 + l16;

  // Q fragments (lane=q, elems=d): MFMA B-operand for S^T = K·Q^T (pre-scaled)
  short8 aqA[2], aqB[2];
#pragma unroll
  for (int kk = 0; kk < 2; ++kk) {
    aqA[kk] = *(const short8*)&Q[(size_t)(rowbase + qA) * DM + colbase + kk * 32 + quad * 8];
    aqB[kk] = *(const short8*)&Q[(size_t)(rowbase + qB) * DM + colbase + kk * 32 + quad * 8];
  }

  float4v oA[4], oB[4];                // O: row q=quad*4+r, col d=dt*16+l16 (k-half partial)
#pragma unroll
  for (int j = 0; j < 4; ++j) { float4v z = {0.f, 0.f, 0.f, 0.f}; oA[j] = z; oB[j] = z; }
  float lA = 0.f, lB = 0.f;            // per-lane partial row-sum, indexed by q = l16

  const short* Kbase0 = K + (size_t)rowbase * DM + colbase;
  const short* Vbase0 = Vt + (size_t)colbase * MTOT + rowbase;

  auto stageK = [&](int kt) {          // K-tile (128 rows x 64 d), 2 GLDS/thread
#pragma unroll
    for (int j = 0; j < 2; ++j) {
      int i = j * 512 + t;
      int n = i >> 3, c = (i & 7) ^ (n & 7);
      GLDS16(Kbase0 + (size_t)(kt * 128 + n) * DM + c * 8, Ks + (j * 512 + wid * 64) * 8);
    }
  };
  auto stageV = [&](int kt) {          // V-tile (64 d x 128 k), 2 GLDS/thread
#pragma unroll
    for (int j = 0; j < 2; ++j) {
      int i = j * 512 + t;
      int d = i >> 4, c = (i & 15) ^ (d & 7);
      GLDS16(Vbase0 + (size_t)d * MTOT + kt * 128 + c * 8, Vs + (j * 512 + wid * 64) * 8);
    }
  };

  stageK(0);
  stageV(0);
  for (int kt = 0; kt < nktB; ++kt) {
    // K(t) landed in all waves; V(t) (2 newest GLDS/thread) stays in flight.
    asm volatile("s_waitcnt vmcnt(2)" ::: "memory");
    __builtin_amdgcn_s_barrier();
    __builtin_amdgcn_sched_barrier(0);

    const bool actA = (kt < nktA);
    const bool diagA = (kt == nktA - 1), diagB = (kt == nktB - 1);

    // --- S^T = K Q^T on this wave's 4 nt-subtiles; exp2; P^T -> strip (b64) ---
#pragma unroll
    for (int ntl = 0; ntl < 4; ++ntl) {
      const int nt = g * 4 + ntl;
      const int n = nt * 16 + l16;
      short8 bk0 = *(const short8*)&Ks[(n * 8 + (quad ^ (n & 7))) * 8];
      short8 bk1 = *(const short8*)&Ks[(n * 8 + ((4 + quad) ^ (n & 7))) * 8];
      const int kb = kt * 128 + nt * 16 + quad * 4;
      float4v zz = {0.f, 0.f, 0.f, 0.f};
      __builtin_amdgcn_s_setprio(1);
      float4v sB = __builtin_amdgcn_mfma_f32_16x16x32_bf16(bk0, aqB[0], zz, 0, 0, 0);
      sB = __builtin_amdgcn_mfma_f32_16x16x32_bf16(bk1, aqB[1], sB, 0, 0, 0);
      float4v sA;
      if (actA) {
        sA = __builtin_amdgcn_mfma_f32_16x16x32_bf16(bk0, aqA[0], zz, 0, 0, 0);
        sA = __builtin_amdgcn_mfma_f32_16x16x32_bf16(bk1, aqA[1], sA, 0, 0, 0);
      }
      __builtin_amdgcn_s_setprio(0);
      float pb[4];
#pragma unroll
      for (int r = 0; r < 4; ++r) {
        float pv = (diagB && (kb + r > qB)) ? 0.f : __builtin_amdgcn_exp2f(sB[r]);
        lB += pv; pb[r] = pv;
      }
      *(int2*)&Pl[1 * 16 * 72 + l16 * 72 + ntl * 16 + quad * 4] =
          make_int2(packbf(pb[0], pb[1]), packbf(pb[2], pb[3]));
      if (actA) {
        float pa[4];
#pragma unroll
        for (int r = 0; r < 4; ++r) {
          float pv = (diagA && (kb + r > qA)) ? 0.f : __builtin_amdgcn_exp2f(sA[r]);
          lA += pv; pa[r] = pv;
        }
        *(int2*)&Pl[0 * 16 * 72 + l16 * 72 + ntl * 16 + quad * 4] =
            make_int2(packbf(pa[0], pa[1]), packbf(pa[2], pa[3]));
      }
    }

    // V(t) landed (only V(t)'s 2 loads outstanding) + everyone done with Ks.
    asm volatile("s_waitcnt vmcnt(0)" ::: "memory");
    __builtin_amdgcn_s_barrier();
    __builtin_amdgcn_sched_barrier(0);

    // K(t+1) prefetch into Ks, hidden under PV(t).
    if (kt + 1 < nktB) stageK(kt + 1);

    // --- O += P V over this wave's 64-k half; V frags shared between tiles ---
#pragma unroll
    for (int kk = 0; kk < 2; ++kk) {
      short8 apB = *(const short8*)&Pl[1 * 16 * 72 + l16 * 72 + kk * 32 + quad * 8];
      short8 apA;
      if (actA) apA = *(const short8*)&Pl[0 * 16 * 72 + l16 * 72 + kk * 32 + quad * 8];
      const int c0 = g * 8 + kk * 4 + quad;     // k-chunk index in Vs
      __builtin_amdgcn_s_setprio(1);
#pragma unroll
      for (int dt = 0; dt < 4; ++dt) {
        const int d = dt * 16 + l16;
        short8 bv = *(const short8*)&Vs[(d * 16 + (c0 ^ (d & 7))) * 8];
        oB[dt] = __builtin_amdgcn_mfma_f32_16x16x32_bf16(apB, bv, oB[dt], 0, 0, 0);
        if (actA) oA[dt] = __builtin_amdgcn_mfma_f32_16x16x32_bf16(apA, bv, oA[dt], 0, 0, 0);
      }
      __builtin_amdgcn_s_setprio(0);
    }

    // Everyone done reading Vs (reads consumed by MFMAs above); release Vs.
    __builtin_amdgcn_s_barrier();
    __builtin_amdgcn_sched_barrier(0);

    // V(t+1) prefetch into Vs, hidden under next iter's S^T phase.
    if (kt + 1 < nktB) stageV(kt + 1);
  }

  // --- quad-reduce lsum within wave (sum over this wave's k-half); per q=l16 ---
  lA += __shfl_xor(lA, 16); lA += __shfl_xor(lA, 32);
  lB += __shfl_xor(lB, 16); lB += __shfl_xor(lB, 32);

  // --- merge the two k-half groups via LDS, then normalize + store (group 0) ---
  __syncthreads();
  float* Ored = (float*)smem;                   // [2 tiles][4 qg][16 q][66]
  float* Lred = (float*)smem + 8448;            // [2 tiles][4 qg][16 q]
  if (g == 1) {
#pragma unroll
    for (int tile = 0; tile < 2; ++tile) {
      const float4v* src = (tile == 0) ? oA : oB;
      const int base = ((tile * 4 + qg) * 16) * 66;
#pragma unroll
      for (int dt = 0; dt < 4; ++dt)
#pragma unroll
        for (int r = 0; r < 4; ++r)
          Ored[base + (quad * 4 + r) * 66 + dt * 16 + l16] = src[dt][r];
    }
    if (lane < 16) {
      Lred[(0 * 4 + qg) * 16 + l16] = lA;
      Lred[(1 * 4 + qg) * 16 + l16] = lB;
    }
  }
  __syncthreads();
  if (g == 0) {
    // totals are indexed by q = l16; O rows are q = quad*4+r -> transpose the
    // normalizer via lane shuffles (source lane s = quad*4+r has l16 == s).
    const float tA = lA + Lred[(0 * 4 + qg) * 16 + l16];
    const float tB = lB + Lred[(1 * 4 + qg) * 16 + l16];
    float iAr[4], iBr[4];
#pragma unroll
    for (int r = 0; r < 4; ++r) {
      iAr[r] = 1.f / __shfl(tA, quad * 4 + r);
      iBr[r] = 1.f / __shfl(tB, quad * 4 + r);
    }
#pragma unroll
    for (int tile = 0; tile < 2; ++tile) {
      const float4v* src = (tile == 0) ? oA : oB;
      const int qt = (tile == 0) ? qtA : qtB;
      const int base = ((tile * 4 + qg) * 16) * 66;
#pragma unroll
      for (int dt = 0; dt < 4; ++dt)
#pragma unroll
        for (int r = 0; r < 4; ++r) {
          float v = src[dt][r] + Ored[base + (quad * 4 + r) * 66 + dt * 16 + l16];
          int grow = rowbase + qt * 64 + qg * 16 + quad * 4 + r;
          int gcol = colbase + dt * 16 + l16;
          O[(size_t)grow * DM + gcol] = f2bf(v * ((tile == 0) ? iAr[r] : iBr[r]));
        }
    }
  }
}

// Output projection (R3-proven original): out = attn x Wo^T, 128m x 64n tiles.
__global__ __launch_bounds__(256, 2) void gemm_out(
    const short* __restrict__ A, const short* __restrict__ B,
    float* __restrict__ out)
{
  __shared__ short As[2][128 * 32];
  __shared__ short Bs[2][64 * 32];
  const int t = threadIdx.x;
  const int w = t >> 6, lane = t & 63;
  const int quad = lane >> 4, l16 = lane & 15;
  const int wm = w >> 1, wn = w & 1;
  const int bm = blockIdx.y * 128, bn = blockIdx.x * 64;

  float4v acc[4][2];
#pragma unroll
  for (int i = 0; i < 4; ++i)
#pragma unroll
    for (int j = 0; j < 2; ++j) { float4v z = {0.f, 0.f, 0.f, 0.f}; acc[i][j] = z; }

  auto stage = [&](int k0, int p) {
#pragma unroll
    for (int i = 0; i < 2; ++i) {
      const int row = (i * 256 + t) >> 2, kc = (i * 256 + t) & 3;
      GLDS16(A + (size_t)(bm + row) * DM + k0 + kc * 8, &As[p][(i * 256 + w * 64) * 8]);
    }
    {
      const int row = t >> 2, kc = t & 3;
      GLDS16(B + (size_t)(bn + row) * DM + k0 + kc * 8, &Bs[p][(w * 64) * 8]);
    }
  };

  stage(0, 0);
  for (int ki = 0; ki < 32; ++ki) {
    const int p = ki & 1;
    __syncthreads();
    if (ki < 31) stage((ki + 1) * 32, p ^ 1);
    short8 af[4], bf[2];
#pragma unroll
    for (int mt = 0; mt < 4; ++mt) af[mt] = *(const short8*)&As[p][(wm * 64 + mt * 16 + l16) * 32 + quad * 8];
#pragma unroll
    for (int nt = 0; nt < 2; ++nt) bf[nt] = *(const short8*)&Bs[p][(wn * 32 + nt * 16 + l16) * 32 + quad * 8];
#pragma unroll
    for (int mt = 0; mt < 4; ++mt)
#pragma unroll
      for (int nt = 0; nt < 2; ++nt)
        acc[mt][nt] = __builtin_amdgcn_mfma_f32_16x16x32_bf16(af[mt], bf[nt], acc[mt][nt], 0, 0, 0);
  }

#pragma unroll
  for (int mt = 0; mt < 4; ++mt)
#pragma unroll
    for (int nt = 0; nt < 2; ++nt)
#pragma unroll
      for (int r = 0; r < 4; ++r) {
        int grow = bm + wm * 64 + mt * 16 + quad * 4 + r;
        int gcol = bn + wn * 32 + nt * 16 + l16;
        out[(size_t)grow * DM + gcol] = acc[mt][nt][r];
      }
}

extern "C" void kernel_launch(void* const* d_in, const int* in_sizes, int n_in,
                              void* d_out, int out_size, void* d_ws, size_t ws_size,
                              hipStream_t stream) {
  const float* x    = (const float*)d_in[0];
  const float* cosp = (const float*)d_in[1];
  const float* sinp = (const float*)d_in[2];
  const float* Wq   = (const float*)d_in[3];
  const float* Wk   = (const float*)d_in[4];
  const float* Wv   = (const float*)d_in[5];
  const float* Wo   = (const float*)d_in[6];

  char* ws = (char*)d_ws;
  const size_t XB = (size_t)MTOT * DM * 2;  // 8 MB
  const size_t WB = (size_t)DM * DM * 2;    // 2 MB
  short* xb    = (short*)(ws);
  short* wqb   = (short*)(ws + XB);
  short* wkb   = (short*)(ws + XB + 1 * WB);
  short* wvb   = (short*)(ws + XB + 2 * WB);
  short* wob   = (short*)(ws + XB + 3 * WB);
  short* Qb    = (short*)(ws + XB + 4 * WB);
  short* Kb    = (short*)(ws + XB + 4 * WB + XB);
  short* Vtb   = (short*)(ws + XB + 4 * WB + 2 * XB);
  short* attnb = xb;  // x dead after QKV GEMMs; reuse its slot

  const int n4tot = (MTOT * DM + 4 * DM * DM) / 4;  // 2,097,152
  hipLaunchKernelGGL(cvt_all, dim3(n4tot / 256), dim3(256), 0, stream,
                     x, Wq, Wk, Wv, Wo, xb, wqb, wkb, wvb, wob);

  hipLaunchKernelGGL(qkv_kernel, dim3(DM / 128, MTOT / 128, 3), dim3(256), 0, stream,
                     xb, wqb, wkb, wvb, Qb, Kb, Vtb, cosp, sinp);

  hipLaunchKernelGGL(attn_kernel, dim3(16, NB * 16), dim3(512), 0, stream,
                     Qb, Kb, Vtb, attnb);

  hipLaunchKernelGGL(gemm_out, dim3(DM / 64, MTOT / 128), dim3(256), 0, stream,
                     attnb, wob, (float*)d_out);
}

// Round 16
// 171.919 us; speedup vs baseline: 1.2892x; 1.0028x over previous
//
#include <hip/hip_runtime.h>
#include <hip/hip_bf16.h>
#include <math.h>

#define DM    1024
#define SEQL  2048
#define NB    2
#define MTOT  4096   // NB*SEQL

typedef __attribute__((ext_vector_type(8))) short short8;
typedef __attribute__((ext_vector_type(4))) short short4v;
typedef __attribute__((ext_vector_type(4))) float float4v;

// async global->LDS, 16B per lane; LDS dest is wave-uniform base (+ lane*16 implicit)
#define GLDS16(g, l) __builtin_amdgcn_global_load_lds( \
    (const __attribute__((address_space(1))) void*)(g), \
    (__attribute__((address_space(3))) void*)(l), 16, 0, 0)

__device__ __forceinline__ short f2bf(float f) {
  union { float f; unsigned u; } c; c.f = f;
  unsigned r = c.u + 0x7FFFu + ((c.u >> 16) & 1u);  // RNE
  return (short)(r >> 16);
}

// pack two fp32 -> dword of two bf16 (lo=a, hi=b); round-half-up (cheap, P>=0)
__device__ __forceinline__ int packbf(float a, float b) {
  union { float f; unsigned u; } ca, cb; ca.f = a; cb.f = b;
  return (int)__builtin_amdgcn_perm(cb.u + 0x8000u, ca.u + 0x8000u, 0x07060302u);
}

// One launch converting x + 4 weights fp32->bf16 (at HBM roofline: 72MB
// @ 6.3TB/s ~ 11.4us).
__global__ __launch_bounds__(256) void cvt_all(
    const float* __restrict__ x, const float* __restrict__ wq, const float* __restrict__ wk,
    const float* __restrict__ wv, const float* __restrict__ wo,
    short* __restrict__ xb, short* __restrict__ wqb, short* __restrict__ wkb,
    short* __restrict__ wvb, short* __restrict__ wob) {
  const int n4x = MTOT * DM / 4;        // 1,048,576
  int i = blockIdx.x * 256 + threadIdx.x;
  const float* s; short* d; int off;
  if (i < n4x) { s = x; d = xb; off = i; }
  else {
    int j = i - n4x;
    int sel = j >> 18;                  // DM*DM/4 = 262144 = 2^18
    off = j & 0x3FFFF;
    s = (sel == 0) ? wq : (sel == 1) ? wk : (sel == 2) ? wv : wo;
    d = (sel == 0) ? wqb : (sel == 1) ? wkb : (sel == 2) ? wvb : wob;
  }
  float4 v = ((const float4*)s)[off];
  short4v o;
  o.x = f2bf(v.x); o.y = f2bf(v.y); o.z = f2bf(v.z); o.w = f2bf(v.w);
  ((short4v*)d)[off] = o;
}

// Fused QKV projection (v14 exact, measured best; XCD remap keeps each
// XCD's 4 A-panels L2-resident: FETCH 40->30MB).
__global__ __launch_bounds__(256, 3) void qkv_kernel(
    const short* __restrict__ A,
    const short* __restrict__ B0, const short* __restrict__ B1, const short* __restrict__ B2,
    short* __restrict__ out0, short* __restrict__ out1, short* __restrict__ out2,
    const float* __restrict__ cosp, const float* __restrict__ sinp)
{
  __shared__ short As[2][128 * 32];
  __shared__ short Bs[2][128 * 32];
  const int t = threadIdx.x;
  const int w = t >> 6, lane = t & 63;
  const int quad = lane >> 4, l16 = lane & 15;
  const int wm = w >> 1, wn = w & 1;

  // XCD remap: h = hw linear id; xcd = h&7 owns y in [xcd*4, xcd*4+4).
  const int h = (blockIdx.z << 8) + (blockIdx.y << 3) + blockIdx.x;
  const int xcd = h & 7, slot = h >> 3;          // slot 0..95
  const int ly = xcd * 4 + (slot & 3);           // 0..31
  const int lx = (slot >> 2) & 7;                // 0..7
  const int lz = slot >> 5;                      // 0..2
  const int bm = ly * 128, bn = lx * 128;

  const short* Bw = (lz == 0) ? B0 : ((lz == 1) ? B1 : B2);

  float4v acc[4][4];
#pragma unroll
  for (int i = 0; i < 4; ++i)
#pragma unroll
    for (int j = 0; j < 4; ++j) { float4v z = {0.f, 0.f, 0.f, 0.f}; acc[i][j] = z; }

  auto stage = [&](int k0, int p) {
#pragma unroll
    for (int i = 0; i < 2; ++i) {
      const int row = (i * 256 + t) >> 2, kc = (i * 256 + t) & 3;
      GLDS16(A  + (size_t)(bm + row) * DM + k0 + kc * 8, &As[p][(i * 256 + w * 64) * 8]);
      GLDS16(Bw + (size_t)(bn + row) * DM + k0 + kc * 8, &Bs[p][(i * 256 + w * 64) * 8]);
    }
  };

  stage(0, 0);
  for (int ki = 0; ki < 32; ++ki) {
    const int p = ki & 1;
    __syncthreads();
    if (ki < 31) stage((ki + 1) * 32, p ^ 1);
    short8 af[4], bf[4];
#pragma unroll
    for (int mt = 0; mt < 4; ++mt) af[mt] = *(const short8*)&As[p][(wm * 64 + mt * 16 + l16) * 32 + quad * 8];
#pragma unroll
    for (int nt = 0; nt < 4; ++nt) bf[nt] = *(const short8*)&Bs[p][(wn * 64 + nt * 16 + l16) * 32 + quad * 8];
#pragma unroll
    for (int mt = 0; mt < 4; ++mt)
#pragma unroll
      for (int nt = 0; nt < 4; ++nt)
        acc[mt][nt] = __builtin_amdgcn_mfma_f32_16x16x32_bf16(af[mt], bf[nt], acc[mt][nt], 0, 0, 0);
  }

  if (lz < 2) {
    short* qo = (lz == 0) ? out0 : out1;
    const float sc = (lz == 0) ? 0.18033688011112042f : 1.0f;  // 0.125*log2(e) for Q
#pragma unroll
    for (int mt = 0; mt < 4; ++mt)
#pragma unroll
      for (int r = 0; r < 4; ++r) {
        int grow = bm + wm * 64 + mt * 16 + quad * 4 + r;
        int s = grow & (SEQL - 1);
        int base = grow * DM + bn + wn * 64;
#pragma unroll
        for (int nt = 0; nt < 2; ++nt) {
          int d1 = nt * 16 + l16;  // 0..31
          float q1 = acc[mt][nt][r], q2 = acc[mt][nt + 2][r];
          float c1 = cosp[s * 64 + d1] * sc,      s1 = sinp[s * 64 + d1] * sc;
          float c2 = cosp[s * 64 + 32 + d1] * sc, s2 = sinp[s * 64 + 32 + d1] * sc;
          qo[base + d1]      = f2bf(q1 * c1 - q2 * s1);
          qo[base + 32 + d1] = f2bf(q2 * c2 + q1 * s2);
        }
      }
  } else {
    short* vo = out2;
#pragma unroll
    for (int mt = 0; mt < 4; ++mt)
#pragma unroll
      for (int nt = 0; nt < 4; ++nt) {
        int gc = bn + wn * 64 + nt * 16 + l16;
        int g0 = bm + wm * 64 + mt * 16 + quad * 4;
        short4v pk;
#pragma unroll
        for (int r = 0; r < 4; ++r) pk[r] = f2bf(acc[mt][nt][r]);
        *(short4v*)&vo[(size_t)gc * MTOT + g0] = pk;
      }
  }
}

// Flash attention v18 (measured best): paired A/B q-tiles, 3-barrier
// counted-vmcnt pipeline, bijective XCD remap (each XCD owns 4 bh-groups
// -> K/V panels L2-resident).
__global__ __launch_bounds__(512, 4) void attn_kernel(
    const short* __restrict__ Q, const short* __restrict__ K,
    const short* __restrict__ Vt, short* __restrict__ O)
{
  __shared__ short smem[34816];        // 68 KB: Ks 16K | Vs 16K | P strips 36K
  short* Ks = smem;                    // [128 n][8 chunks], xor-swizzled
  short* Vs = smem + 8192;             // [64 d][16 chunks], xor-swizzled
  const int t = threadIdx.x;
  const int wid = t >> 6, lane = t & 63;
  const int quad = lane >> 4, l16 = lane & 15;
  const int g = wid >> 2;              // k-half group: 0 -> k 0..63, 1 -> 64..127
  const int qg = wid & 3;              // q-row group (16 rows)
  short* Pl = smem + 16384 + wid * (2 * 16 * 72);  // per-wave strips [2 tiles][16 q][72]

  // XCD remap: hw linear id -> xcd owns bh in [xcd*4, xcd*4+4), all q-pairs.
  const int hw = (blockIdx.y << 4) + blockIdx.x;   // 0..511
  const int xcd = hw & 7, slot = hw >> 3;          // slot 0..63
  const int bh = xcd * 4 + (slot & 3);             // 0..31
  const int qp = slot >> 2;                        // 0..15
  const int qtA = qp, qtB = 31 - qp;
  const int b = bh >> 4, h = bh & 15;
  const int rowbase = b * SEQL, colbase = h * 64;
  const int nktA = (qtA >> 1) + 1, nktB = (qtB >> 1) + 1;
  const int qA = qtA * 64 + qg * 16 + l16;
  const int qB = qtB * 64 + qg * 16 + l16;

  // Q fragments (lane=q, elems=d): MFMA B-operand for S^T = K·Q^T (pre-scaled)
  short8 aqA[2], aqB[2];
#pragma unroll
  for (int kk = 0; kk < 2; ++kk) {
    aqA[kk] = *(const short8*)&Q[(size_t)(rowbase + qA) * DM + colbase + kk * 32 + quad * 8];
    aqB[kk] = *(const short8*)&Q[(size_t)(rowbase + qB) * DM + colbase + kk * 32 + quad * 8];
  }

  float4v oA[4], oB[4];                // O: row q=quad*4+r, col d=dt*16+l16 (k-half partial)
#pragma unroll
  for (int j = 0; j < 4; ++j) { float4v z = {0.f, 0.f, 0.f, 0.f}; oA[j] = z; oB[j] = z; }
  float lA = 0.f, lB = 0.f;            // per-lane partial row-sum, indexed by q = l16

  const short* Kbase0 = K + (size_t)rowbase * DM + colbase;
  const short* Vbase0 = Vt + (size_t)colbase * MTOT + rowbase;

  auto stageK = [&](int kt) {          // K-tile (128 rows x 64 d), 2 GLDS/thread
#pragma unroll
    for (int j = 0; j < 2; ++j) {
      int i = j * 512 + t;
      int n = i >> 3, c = (i & 7) ^ (n & 7);
      GLDS16(Kbase0 + (size_t)(kt * 128 + n) * DM + c * 8, Ks + (j * 512 + wid * 64) * 8);
    }
  };
  auto stageV = [&](int kt) {          // V-tile (64 d x 128 k), 2 GLDS/thread
#pragma unroll
    for (int j = 0; j < 2; ++j) {
      int i = j * 512 + t;
      int d = i >> 4, c = (i & 15) ^ (d & 7);
      GLDS16(Vbase0 + (size_t)d * MTOT + kt * 128 + c * 8, Vs + (j * 512 + wid * 64) * 8);
    }
  };

  stageK(0);
  stageV(0);
  for (int kt = 0; kt < nktB; ++kt) {
    // K(t) landed in all waves; V(t) (2 newest GLDS/thread) stays in flight.
    asm volatile("s_waitcnt vmcnt(2)" ::: "memory");
    __builtin_amdgcn_s_barrier();
    __builtin_amdgcn_sched_barrier(0);

    const bool actA = (kt < nktA);
    const bool diagA = (kt == nktA - 1), diagB = (kt == nktB - 1);

    // --- S^T = K Q^T on this wave's 4 nt-subtiles; exp2; P^T -> strip (b64) ---
#pragma unroll
    for (int ntl = 0; ntl < 4; ++ntl) {
      const int nt = g * 4 + ntl;
      const int n = nt * 16 + l16;
      short8 bk0 = *(const short8*)&Ks[(n * 8 + (quad ^ (n & 7))) * 8];
      short8 bk1 = *(const short8*)&Ks[(n * 8 + ((4 + quad) ^ (n & 7))) * 8];
      const int kb = kt * 128 + nt * 16 + quad * 4;
      float4v zz = {0.f, 0.f, 0.f, 0.f};
      __builtin_amdgcn_s_setprio(1);
      float4v sB = __builtin_amdgcn_mfma_f32_16x16x32_bf16(bk0, aqB[0], zz, 0, 0, 0);
      sB = __builtin_amdgcn_mfma_f32_16x16x32_bf16(bk1, aqB[1], sB, 0, 0, 0);
      float4v sA;
      if (actA) {
        sA = __builtin_amdgcn_mfma_f32_16x16x32_bf16(bk0, aqA[0], zz, 0, 0, 0);
        sA = __builtin_amdgcn_mfma_f32_16x16x32_bf16(bk1, aqA[1], sA, 0, 0, 0);
      }
      __builtin_amdgcn_s_setprio(0);
      float pb[4];
#pragma unroll
      for (int r = 0; r < 4; ++r) {
        float pv = (diagB && (kb + r > qB)) ? 0.f : __builtin_amdgcn_exp2f(sB[r]);
        lB += pv; pb[r] = pv;
      }
      *(int2*)&Pl[1 * 16 * 72 + l16 * 72 + ntl * 16 + quad * 4] =
          make_int2(packbf(pb[0], pb[1]), packbf(pb[2], pb[3]));
      if (actA) {
        float pa[4];
#pragma unroll
        for (int r = 0; r < 4; ++r) {
          float pv = (diagA && (kb + r > qA)) ? 0.f : __builtin_amdgcn_exp2f(sA[r]);
          lA += pv; pa[r] = pv;
        }
        *(int2*)&Pl[0 * 16 * 72 + l16 * 72 + ntl * 16 + quad * 4] =
            make_int2(packbf(pa[0], pa[1]), packbf(pa[2], pa[3]));
      }
    }

    // V(t) landed (only V(t)'s 2 loads outstanding) + everyone done with Ks.
    asm volatile("s_waitcnt vmcnt(0)" ::: "memory");
    __builtin_amdgcn_s_barrier();
    __builtin_amdgcn_sched_barrier(0);

    // K(t+1) prefetch into Ks, hidden under PV(t).
    if (kt + 1 < nktB) stageK(kt + 1);

    // --- O += P V over this wave's 64-k half; V frags shared between tiles ---
#pragma unroll
    for (int kk = 0; kk < 2; ++kk) {
      short8 apB = *(const short8*)&Pl[1 * 16 * 72 + l16 * 72 + kk * 32 + quad * 8];
      short8 apA;
      if (actA) apA = *(const short8*)&Pl[0 * 16 * 72 + l16 * 72 + kk * 32 + quad * 8];
      const int c0 = g * 8 + kk * 4 + quad;     // k-chunk index in Vs
      __builtin_amdgcn_s_setprio(1);
#pragma unroll
      for (int dt = 0; dt < 4; ++dt) {
        const int d = dt * 16 + l16;
        short8 bv = *(const short8*)&Vs[(d * 16 + (c0 ^ (d & 7))) * 8];
        oB[dt] = __builtin_amdgcn_mfma_f32_16x16x32_bf16(apB, bv, oB[dt], 0, 0, 0);
        if (actA) oA[dt] = __builtin_amdgcn_mfma_f32_16x16x32_bf16(apA, bv, oA[dt], 0, 0, 0);
      }
      __builtin_amdgcn_s_setprio(0);
    }

    // Everyone done reading Vs (reads consumed by MFMAs above); release Vs.
    __builtin_amdgcn_s_barrier();
    __builtin_amdgcn_sched_barrier(0);

    // V(t+1) prefetch into Vs, hidden under next iter's S^T phase.
    if (kt + 1 < nktB) stageV(kt + 1);
  }

  // --- quad-reduce lsum within wave (sum over this wave's k-half); per q=l16 ---
  lA += __shfl_xor(lA, 16); lA += __shfl_xor(lA, 32);
  lB += __shfl_xor(lB, 16); lB += __shfl_xor(lB, 32);

  // --- merge the two k-half groups via LDS, then normalize + store (group 0) ---
  __syncthreads();
  float* Ored = (float*)smem;                   // [2 tiles][4 qg][16 q][66]
  float* Lred = (float*)smem + 8448;            // [2 tiles][4 qg][16 q]
  if (g == 1) {
#pragma unroll
    for (int tile = 0; tile < 2; ++tile) {
      const float4v* src = (tile == 0) ? oA : oB;
      const int base = ((tile * 4 + qg) * 16) * 66;
#pragma unroll
      for (int dt = 0; dt < 4; ++dt)
#pragma unroll
        for (int r = 0; r < 4; ++r)
          Ored[base + (quad * 4 + r) * 66 + dt * 16 + l16] = src[dt][r];
    }
    if (lane < 16) {
      Lred[(0 * 4 + qg) * 16 + l16] = lA;
      Lred[(1 * 4 + qg) * 16 + l16] = lB;
    }
  }
  __syncthreads();
  if (g == 0) {
    // totals are indexed by q = l16; O rows are q = quad*4+r -> transpose the
    // normalizer via lane shuffles (source lane s = quad*4+r has l16 == s).
    const float tA = lA + Lred[(0 * 4 + qg) * 16 + l16];
    const float tB = lB + Lred[(1 * 4 + qg) * 16 + l16];
    float iAr[4], iBr[4];
#pragma unroll
    for (int r = 0; r < 4; ++r) {
      iAr[r] = 1.f / __shfl(tA, quad * 4 + r);
      iBr[r] = 1.f / __shfl(tB, quad * 4 + r);
    }
#pragma unroll
    for (int tile = 0; tile < 2; ++tile) {
      const float4v* src = (tile == 0) ? oA : oB;
      const int qt = (tile == 0) ? qtA : qtB;
      const int base = ((tile * 4 + qg) * 16) * 66;
#pragma unroll
      for (int dt = 0; dt < 4; ++dt)
#pragma unroll
        for (int r = 0; r < 4; ++r) {
          float v = src[dt][r] + Ored[base + (quad * 4 + r) * 66 + dt * 16 + l16];
          int grow = rowbase + qt * 64 + qg * 16 + quad * 4 + r;
          int gcol = colbase + dt * 16 + l16;
          O[(size_t)grow * DM + gcol] = f2bf(v * ((tile == 0) ? iAr[r] : iBr[r]));
        }
    }
  }
}

// Output projection v19: R3 structure + XCD remap (the last kernel on
// default dispatch; same proven mechanism — each XCD owns 4 row-panels
// x all 16 col-tiles, A working set 1MB L2-resident).
__global__ __launch_bounds__(256, 2) void gemm_out(
    const short* __restrict__ A, const short* __restrict__ B,
    float* __restrict__ out)
{
  __shared__ short As[2][128 * 32];
  __shared__ short Bs[2][64 * 32];
  const int t = threadIdx.x;
  const int w = t >> 6, lane = t & 63;
  const int quad = lane >> 4, l16 = lane & 15;
  const int wm = w >> 1, wn = w & 1;

  // XCD remap: hw linear id -> xcd owns row-panels [xcd*4, xcd*4+4).
  const int hw = (blockIdx.y << 4) + blockIdx.x;   // 0..511
  const int xcd = hw & 7, slot = hw >> 3;          // slot 0..63
  const int ly = xcd * 4 + (slot & 3);             // 0..31 row tile
  const int lx = slot >> 2;                        // 0..15 col tile
  const int bm = ly * 128, bn = lx * 64;

  float4v acc[4][2];
#pragma unroll
  for (int i = 0; i < 4; ++i)
#pragma unroll
    for (int j = 0; j < 2; ++j) { float4v z = {0.f, 0.f, 0.f, 0.f}; acc[i][j] = z; }

  auto stage = [&](int k0, int p) {
#pragma unroll
    for (int i = 0; i < 2; ++i) {
      const int row = (i * 256 + t) >> 2, kc = (i * 256 + t) & 3;
      GLDS16(A + (size_t)(bm + row) * DM + k0 + kc * 8, &As[p][(i * 256 + w * 64) * 8]);
    }
    {
      const int row = t >> 2, kc = t & 3;
      GLDS16(B + (size_t)(bn + row) * DM + k0 + kc * 8, &Bs[p][(w * 64) * 8]);
    }
  };

  stage(0, 0);
  for (int ki = 0; ki < 32; ++ki) {
    const int p = ki & 1;
    __syncthreads();
    if (ki < 31) stage((ki + 1) * 32, p ^ 1);
    short8 af[4], bf[2];
#pragma unroll
    for (int mt = 0; mt < 4; ++mt) af[mt] = *(const short8*)&As[p][(wm * 64 + mt * 16 + l16) * 32 + quad * 8];
#pragma unroll
    for (int nt = 0; nt < 2; ++nt) bf[nt] = *(const short8*)&Bs[p][(wn * 32 + nt * 16 + l16) * 32 + quad * 8];
#pragma unroll
    for (int mt = 0; mt < 4; ++mt)
#pragma unroll
      for (int nt = 0; nt < 2; ++nt)
        acc[mt][nt] = __builtin_amdgcn_mfma_f32_16x16x32_bf16(af[mt], bf[nt], acc[mt][nt], 0, 0, 0);
  }

#pragma unroll
  for (int mt = 0; mt < 4; ++mt)
#pragma unroll
    for (int nt = 0; nt < 2; ++nt)
#pragma unroll
      for (int r = 0; r < 4; ++r) {
        int grow = bm + wm * 64 + mt * 16 + quad * 4 + r;
        int gcol = bn + wn * 32 + nt * 16 + l16;
        out[(size_t)grow * DM + gcol] = acc[mt][nt][r];
      }
}

extern "C" void kernel_launch(void* const* d_in, const int* in_sizes, int n_in,
                              void* d_out, int out_size, void* d_ws, size_t ws_size,
                              hipStream_t stream) {
  const float* x    = (const float*)d_in[0];
  const float* cosp = (const float*)d_in[1];
  const float* sinp = (const float*)d_in[2];
  const float* Wq   = (const float*)d_in[3];
  const float* Wk   = (const float*)d_in[4];
  const float* Wv   = (const float*)d_in[5];
  const float* Wo   = (const float*)d_in[6];

  char* ws = (char*)d_ws;
  const size_t XB = (size_t)MTOT * DM * 2;  // 8 MB
  const size_t WB = (size_t)DM * DM * 2;    // 2 MB
  short* xb    = (short*)(ws);
  short* wqb   = (short*)(ws + XB);
  short* wkb   = (short*)(ws + XB + 1 * WB);
  short* wvb   = (short*)(ws + XB + 2 * WB);
  short* wob   = (short*)(ws + XB + 3 * WB);
  short* Qb    = (short*)(ws + XB + 4 * WB);
  short* Kb    = (short*)(ws + XB + 4 * WB + XB);
  short* Vtb   = (short*)(ws + XB + 4 * WB + 2 * XB);
  short* attnb = xb;  // x dead after QKV GEMMs; reuse its slot

  const int n4tot = (MTOT * DM + 4 * DM * DM) / 4;  // 2,097,152
  hipLaunchKernelGGL(cvt_all, dim3(n4tot / 256), dim3(256), 0, stream,
                     x, Wq, Wk, Wv, Wo, xb, wqb, wkb, wvb, wob);

  hipLaunchKernelGGL(qkv_kernel, dim3(DM / 128, MTOT / 128, 3), dim3(256), 0, stream,
                     xb, wqb, wkb, wvb, Qb, Kb, Vtb, cosp, sinp);

  hipLaunchKernelGGL(attn_kernel, dim3(16, NB * 16), dim3(512), 0, stream,
                     Qb, Kb, Vtb, attnb);

  hipLaunchKernelGGL(gemm_out, dim3(DM / 64, MTOT / 128), dim3(256), 0, stream,
                     attnb, wob, (float*)d_out);
}